// Round 2
// 309.420 us; speedup vs baseline: 1.1196x; 1.1196x over previous
//
#include <hip/hip_runtime.h>
#include <hip/hip_bf16.h>
#include <math.h>

#define IN_DIM 256
#define NH 4
#define HD 128

typedef __attribute__((ext_vector_type(8))) short short8;
typedef __attribute__((ext_vector_type(4))) float floatx4;
typedef __attribute__((ext_vector_type(2))) float floatx2;

__device__ __forceinline__ unsigned short f2bf(float f) {
    __hip_bfloat16 h = __float2bfloat16(f);
    return *reinterpret_cast<unsigned short*>(&h);
}
__device__ __forceinline__ float asf(unsigned int u) {
    union { unsigned int i; float f; } c; c.i = u; return c.f;
}

// K0: CSR row pointers from sorted row[].
__global__ __launch_bounds__(256) void build_rowptr_k(const int* __restrict__ row,
                                                      int* __restrict__ rowptr,
                                                      int E, int N) {
    int e = blockIdx.x * blockDim.x + threadIdx.x;
    if (e >= E) return;
    int r = row[e];
    int rprev = (e > 0) ? row[e - 1] : -1;
    for (int rr = rprev + 1; rr <= r; ++rr) rowptr[rr] = e;
    if (e == E - 1) {
        for (int rr = r + 1; rr <= N; ++rr) rowptr[rr] = E;
    }
}

// Kp: [ll_w; lr_w] (2 x 128 x 256 fp32) -> Wb (256 x 256 bf16 row-major [col][k])
__global__ __launch_bounds__(256) void prep_w_k(const float* __restrict__ ll_w,
                                                const float* __restrict__ lr_w,
                                                unsigned short* __restrict__ Wb) {
    int idx = blockIdx.x * 256 + threadIdx.x;
    int j = idx >> 8, k = idx & 255;
    float v = (j < 128) ? ll_w[(size_t)j * 256 + k] : lr_w[(size_t)(j - 128) * 256 + k];
    Wb[idx] = f2bf(v);
}

// Ka: per-node exp(attn2) logits (fp32 exact, exp folded in here so the edge
// kernel's gather feeds FMAs directly) + x -> bf16 conversion (xb).
// One wave per node.
__global__ __launch_bounds__(256) void attn_conv_k(
    const float* __restrict__ x,
    const float* __restrict__ a2_w, const float* __restrict__ a2_b,
    float* __restrict__ eattn, unsigned short* __restrict__ xb, int N)
{
    const int n = blockIdx.x * 4 + (threadIdx.x >> 6);
    const int lane = threadIdx.x & 63;
    if (n >= N) return;
    const float4 xv = ((const float4*)x)[(size_t)n * 64 + lane];
    ushort4 pk;
    pk.x = f2bf(xv.x); pk.y = f2bf(xv.y); pk.z = f2bf(xv.z); pk.w = f2bf(xv.w);
    *(ushort4*)(xb + (size_t)n * IN_DIM + lane * 4) = pk;
    #pragma unroll
    for (int c = 0; c < 4; ++c) {
        const float4 wv = ((const float4*)(a2_w + (size_t)c * IN_DIM))[lane];
        float p = xv.x * wv.x + xv.y * wv.y + xv.z * wv.z + xv.w * wv.w;
        #pragma unroll
        for (int o = 32; o; o >>= 1) p += __shfl_xor(p, o, 64);
        if (lane == 0) eattn[(size_t)n * NH + c] = __expf(p + a2_b[c]);
    }
}

// K1: persistent streaming GEMM C[N x 256] = xb . Wb^T.
// 512 threads = 8 waves; wave w owns cols 32w..32w+31, B-frags held in registers
// for the whole kernel. Per 32-row slab: A staged to padded LDS (reg-prefetched
// one slab ahead), 32 MFMA/wave, LDS-transposed epilogue for coalesced stores.
// cols 0..127 (+ll_b) -> xwb bf16; cols 128..255 (+lr_b) -> out fp32.
__global__ __launch_bounds__(512, 4) void node_gemm_k(
    const unsigned short* __restrict__ xb, const unsigned short* __restrict__ Wb,
    const float* __restrict__ ll_b, const float* __restrict__ lr_b,
    unsigned short* __restrict__ xwb, float* __restrict__ out, int N)
{
    __shared__ unsigned short Abuf[2][32 * 264];  // 33792 B, row stride 528 B (33x16, 2-way bank alias)
    __shared__ unsigned short LdsX[32 * 136];     //  8704 B, row stride 272 B
    __shared__ float          LdsO[32 * 132];     // 16896 B, row stride 528 B

    const int tid = threadIdx.x;
    const int lane = tid & 63;
    const int w = tid >> 6;            // 0..7
    const int lo = lane & 15;
    const int hi = lane >> 4;          // 0..3

    // B fragments in registers: wave w, col-tile ct -> col = 32w + 16ct + lo.
    // frag for k-step s: lane holds Wb[col][32s + 8hi .. +7].
    short8 Bf[2][8];
    int cols[2]; float bias[2];
    #pragma unroll
    for (int ct = 0; ct < 2; ++ct) {
        const int col = w * 32 + ct * 16 + lo;
        cols[ct] = col;
        bias[ct] = (col < HD) ? ll_b[col] : lr_b[col - HD];
        #pragma unroll
        for (int s = 0; s < 8; ++s)
            Bf[ct][s] = *(const short8*)(Wb + (size_t)col * IN_DIM + s * 32 + hi * 8);
    }

    // staging: thread t covers slab-row tr = t>>4, 32 B at element offset (t&15)*16
    const int tr = tid >> 4;
    const int tk = (tid & 15) * 16;

    uint4 st0, st1;
    auto gload = [&](int slab) {
        int rg = slab * 32 + tr;
        if (rg >= N) rg = 0;                        // clamped safe address
        const uint4* p = (const uint4*)(xb + (size_t)rg * IN_DIM + tk);
        st0 = p[0]; st1 = p[1];
    };

    const int nslab = (N + 31) >> 5;
    int slab = blockIdx.x;
    gload(slab);
    int pb = 0;

    for (; slab < nslab; slab += gridDim.x) {
        unsigned short* ab = &Abuf[pb][0];
        // stage prefetched regs -> LDS
        *(uint4*)(ab + tr * 264 + tk) = st0;
        *(uint4*)(ab + tr * 264 + tk + 8) = st1;
        __syncthreads();

        // prefetch next slab into regs (lands during this slab's compute+epilogue)
        const int next = slab + gridDim.x;
        if (next < nslab) gload(next);

        floatx4 acc[2][2];
        #pragma unroll
        for (int rt = 0; rt < 2; ++rt)
            #pragma unroll
            for (int ct = 0; ct < 2; ++ct)
                acc[rt][ct] = (floatx4){0.f, 0.f, 0.f, 0.f};

        #pragma unroll
        for (int s = 0; s < 8; ++s) {
            // A-frag: lane holds A[m = 16rt + lo][k = 32s + 8hi .. +7]
            const short8 A0 = *(const short8*)(ab + lo * 264 + s * 32 + hi * 8);
            const short8 A1 = *(const short8*)(ab + (16 + lo) * 264 + s * 32 + hi * 8);
            acc[0][0] = __builtin_amdgcn_mfma_f32_16x16x32_bf16(A0, Bf[0][s], acc[0][0], 0, 0, 0);
            acc[0][1] = __builtin_amdgcn_mfma_f32_16x16x32_bf16(A0, Bf[1][s], acc[0][1], 0, 0, 0);
            acc[1][0] = __builtin_amdgcn_mfma_f32_16x16x32_bf16(A1, Bf[0][s], acc[1][0], 0, 0, 0);
            acc[1][1] = __builtin_amdgcn_mfma_f32_16x16x32_bf16(A1, Bf[1][s], acc[1][1], 0, 0, 0);
        }

        // E: accumulators -> epilogue LDS (C/D layout: col = lo, row = 4hi + reg)
        #pragma unroll
        for (int rt = 0; rt < 2; ++rt)
            #pragma unroll
            for (int ct = 0; ct < 2; ++ct) {
                const int c = cols[ct];
                #pragma unroll
                for (int j = 0; j < 4; ++j) {
                    const int r = rt * 16 + hi * 4 + j;
                    const float v = acc[rt][ct][j] + bias[ct];
                    if (c < HD) LdsX[r * 136 + c] = f2bf(v);
                    else        LdsO[r * 132 + (c - HD)] = v;
                }
            }

        // F: LDS-visibility barrier WITHOUT draining the global prefetch (vmcnt untouched)
        asm volatile("s_waitcnt lgkmcnt(0)\n\ts_barrier" ::: "memory");

        // G: coalesced stores from epilogue LDS
        {
            const int rg = slab * 32 + tr;
            if (rg < N) {
                *(uint4*)(xwb + (size_t)rg * HD + (tid & 15) * 8) =
                    *(const uint4*)(LdsX + tr * 136 + (tid & 15) * 8);
                float4* od = (float4*)(out + (size_t)rg * HD + (tid & 15) * 8);
                const float* lsrc = LdsO + tr * 132 + (tid & 15) * 8;
                od[0] = *(const float4*)(lsrc);
                od[1] = *(const float4*)(lsrc + 4);
            }
        }
        pb ^= 1;
    }
}

// K2: single-pass fused softmax + aggregation. One wave per destination node.
// Latency-bound gather loop -> unroll 4 with a 2-stage software pipeline:
// group g's 8 gathers (4 eattn + 4 xwb rows) are in flight while group g+1's
// col indices load. exp() is precomputed per-node in attn_conv_k, so the
// gathered weight feeds the FMA directly. rowptr bounds go through
// readfirstlane so loop control + col loads take the scalar path.
__global__ __launch_bounds__(256) void edge_aggregate_k(
    const int* __restrict__ rowptr, const int* __restrict__ col,
    const float* __restrict__ eattn,
    const unsigned short* __restrict__ xwb, float* __restrict__ out, int N)
{
    const int n = blockIdx.x * 4 + (threadIdx.x >> 6);
    const int lane = threadIdx.x & 63;
    if (n >= N) return;
    const int e0 = __builtin_amdgcn_readfirstlane(rowptr[n]);
    const int e1 = __builtin_amdgcn_readfirstlane(rowptr[n + 1]);
    if (e0 >= e1) return;   // isolated node: out keeps lin_r base

    const int h = lane >> 4;          // head of dims 2*lane, 2*lane+1
    const int d2 = 2 * lane;

    // issue the out RMW load early; non-temporal so this one-shot 102 MB
    // stream doesn't evict the xwb gather table from L2
    floatx2* op = (floatx2*)(out + (size_t)n * HD + d2);
    floatx2 o = __builtin_nontemporal_load(op);

    float s = 0.f, acc0 = 0.f, acc1 = 0.f;
    int e = e0;

    if (e + 4 <= e1) {
        int c0 = col[e], c1 = col[e + 1], c2 = col[e + 2], c3 = col[e + 3];
        for (; e + 8 <= e1; e += 4) {
            // 8 independent gathers for the current group
            const float w0 = eattn[c0 * NH + h];
            const float w1 = eattn[c1 * NH + h];
            const float w2 = eattn[c2 * NH + h];
            const float w3 = eattn[c3 * NH + h];
            const unsigned int p0 = *(const unsigned int*)(xwb + c0 * HD + d2);
            const unsigned int p1 = *(const unsigned int*)(xwb + c1 * HD + d2);
            const unsigned int p2 = *(const unsigned int*)(xwb + c2 * HD + d2);
            const unsigned int p3 = *(const unsigned int*)(xwb + c3 * HD + d2);
            // next group's indices load while the gathers are in flight
            const int n0 = col[e + 4];
            const int n1 = col[e + 5];
            const int n2 = col[e + 6];
            const int n3 = col[e + 7];
            s += (w0 + w1) + (w2 + w3);
            acc0 += w0 * asf(p0 << 16) + w1 * asf(p1 << 16);
            acc0 += w2 * asf(p2 << 16) + w3 * asf(p3 << 16);
            acc1 += w0 * asf(p0 & 0xffff0000u) + w1 * asf(p1 & 0xffff0000u);
            acc1 += w2 * asf(p2 & 0xffff0000u) + w3 * asf(p3 & 0xffff0000u);
            c0 = n0; c1 = n1; c2 = n2; c3 = n3;
        }
        // drain: last full group of 4
        {
            const float w0 = eattn[c0 * NH + h];
            const float w1 = eattn[c1 * NH + h];
            const float w2 = eattn[c2 * NH + h];
            const float w3 = eattn[c3 * NH + h];
            const unsigned int p0 = *(const unsigned int*)(xwb + c0 * HD + d2);
            const unsigned int p1 = *(const unsigned int*)(xwb + c1 * HD + d2);
            const unsigned int p2 = *(const unsigned int*)(xwb + c2 * HD + d2);
            const unsigned int p3 = *(const unsigned int*)(xwb + c3 * HD + d2);
            s += (w0 + w1) + (w2 + w3);
            acc0 += w0 * asf(p0 << 16) + w1 * asf(p1 << 16);
            acc0 += w2 * asf(p2 << 16) + w3 * asf(p3 << 16);
            acc1 += w0 * asf(p0 & 0xffff0000u) + w1 * asf(p1 & 0xffff0000u);
            acc1 += w2 * asf(p2 & 0xffff0000u) + w3 * asf(p3 & 0xffff0000u);
            e += 4;
        }
    }
    // tail: 0..3 edges
    for (; e < e1; ++e) {
        const int c0 = col[e];
        const float w0 = eattn[c0 * NH + h];
        const unsigned int p0 = *(const unsigned int*)(xwb + c0 * HD + d2);
        s += w0;
        acc0 += w0 * asf(p0 << 16);
        acc1 += w0 * asf(p0 & 0xffff0000u);
    }

    const float inv = 1.f / s;
    o.x += acc0 * inv;
    o.y += acc1 * inv;
    __builtin_nontemporal_store(o, op);
}

extern "C" void kernel_launch(void* const* d_in, const int* in_sizes, int n_in,
                              void* d_out, int out_size, void* d_ws, size_t ws_size,
                              hipStream_t stream) {
    const float* x    = (const float*)d_in[0];
    const int*   row  = (const int*)d_in[1];
    const int*   col  = (const int*)d_in[2];
    const float* a2_w = (const float*)d_in[5];
    const float* a2_b = (const float*)d_in[6];
    const float* ll_w = (const float*)d_in[7];
    const float* ll_b = (const float*)d_in[8];
    const float* lr_w = (const float*)d_in[9];
    const float* lr_b = (const float*)d_in[10];
    float* out = (float*)d_out;

    const int N = in_sizes[0] / IN_DIM;
    const int E = in_sizes[1];

    // ws layout: rowptr | eattn | xwb (bf16) | Wb (bf16) | xb (bf16)  (~79 MB)
    char* ws = (char*)d_ws;
    size_t off = ((size_t)(N + 1) * sizeof(int) + 255) & ~(size_t)255;
    int*   rowptr = (int*)ws;
    float* eattn  = (float*)(ws + off); off += (size_t)N * NH * sizeof(float);
    unsigned short* xwb = (unsigned short*)(ws + off); off += (size_t)N * HD * sizeof(unsigned short);
    unsigned short* Wb  = (unsigned short*)(ws + off); off += (size_t)256 * IN_DIM * sizeof(unsigned short);
    unsigned short* xb  = (unsigned short*)(ws + off); off += (size_t)N * IN_DIM * sizeof(unsigned short);

    prep_w_k<<<256, 256, 0, stream>>>(ll_w, lr_w, Wb);
    build_rowptr_k<<<(E + 255) / 256, 256, 0, stream>>>(row, rowptr, E, N);
    attn_conv_k<<<(N + 3) / 4, 256, 0, stream>>>(x, a2_w, a2_b, eattn, xb, N);
    node_gemm_k<<<512, 512, 0, stream>>>(xb, Wb, ll_b, lr_b, xwb, out, N);
    edge_aggregate_k<<<(N + 3) / 4, 256, 0, stream>>>(rowptr, col, eattn, xwb, out, N);
}